// Round 1
// baseline (640.823 us; speedup 1.0000x reference)
//
#include <hip/hip_runtime.h>
#include <hip/hip_bf16.h>
#include <math.h>

#define TOKENS 2048
#define IN_DIM 2048
#define VOCAB  32000

#define BM 128
#define BN 128
#define BK 64
#define GEMM_GRID ((TOKENS / BM) * (VOCAB / BN))  // 16 * 250 = 4000

typedef short s16x8 __attribute__((ext_vector_type(8)));
typedef float f32x4 __attribute__((ext_vector_type(4)));

// ---------- fp32 -> bf16 (round-to-nearest-even) ----------
__device__ __forceinline__ unsigned short f2bf_rne(float f) {
  unsigned int u = __float_as_uint(f);
  u += 0x7fffu + ((u >> 16) & 1u);
  return (unsigned short)(u >> 16);
}

__global__ __launch_bounds__(256) void convert_f32_to_bf16(
    const float* __restrict__ in, unsigned short* __restrict__ out, int n4) {
  int idx = blockIdx.x * blockDim.x + threadIdx.x;
  int stride = gridDim.x * blockDim.x;
  for (int i = idx; i < n4; i += stride) {
    float4 v = reinterpret_cast<const float4*>(in)[i];
    ushort4 o;
    o.x = f2bf_rne(v.x);
    o.y = f2bf_rne(v.y);
    o.z = f2bf_rne(v.z);
    o.w = f2bf_rne(v.w);
    reinterpret_cast<ushort4*>(out)[i] = o;
  }
}

// ---------- async global -> LDS, 16B per lane ----------
__device__ __forceinline__ void gload_lds16(const unsigned short* g, unsigned short* l) {
  __builtin_amdgcn_global_load_lds(
      (const __attribute__((address_space(1))) unsigned int*)g,
      (__attribute__((address_space(3))) unsigned int*)l, 16, 0, 0);
}

// ---------- GEMM: C[t][v] = sum_k Xbf[t][k] * Wbf[v][k] ----------
// Both operands K-major ("B^T" layout). 128x128 tile, 4 waves (2x2 of 64x64),
// mfma_f32_16x16x32_bf16. LDS tiles [128][64] bf16 with st-style XOR swizzle
// applied via pre-swizzled global source (global_load_lds writes linearly).
__global__ __launch_bounds__(256) void gemm_bt(
    const unsigned short* __restrict__ A,   // [TOKENS][IN_DIM] bf16
    const unsigned short* __restrict__ B,   // [VOCAB][IN_DIM] bf16
    float* __restrict__ C) {                // [TOKENS][VOCAB] logits
  __shared__ __align__(16) unsigned short ldsA[BM * BK];
  __shared__ __align__(16) unsigned short ldsB[BN * BK];

  const int tid = threadIdx.x;
  const int lane = tid & 63;
  const int wave = tid >> 6;
  const int wr = wave >> 1;  // wave row (0..1)
  const int wc = wave & 1;   // wave col (0..1)

  // XCD-aware swizzle (4000 % 8 == 0 -> simple form), then panel-major:
  // 16 consecutive logical ids share one B column panel (512 KB -> L2 reuse).
  const int bid = blockIdx.x;
  const int per = GEMM_GRID / 8;
  const int lid = (bid & 7) * per + (bid >> 3);
  const int rowTile = lid & 15;
  const int colTile = lid >> 4;
  const int rowBase = rowTile * BM;
  const int colBase = colTile * BN;

  // Staging: 1024 16B-chunks per tile; 4 per thread per K-step.
  // chunk ch: row = ch>>3, stored c16 = ch&7 holds global c16 ^ (row&7).
  int sRow[4], sCol[4];
#pragma unroll
  for (int it = 0; it < 4; ++it) {
    int ch = it * 256 + tid;
    int row = ch >> 3, c16 = ch & 7;
    sRow[it] = row;
    sCol[it] = ((c16 ^ (row & 7)) << 3);  // element offset in [0,64)
  }

  // ds_read offsets (ushort units), swizzle applied on read.
  int offA[2][4], offB[2][4];
#pragma unroll
  for (int kk = 0; kk < 2; ++kk) {
#pragma unroll
    for (int m = 0; m < 4; ++m) {
      int c16 = kk * 4 + (lane >> 4);
      int rowA = wr * 64 + m * 16 + (lane & 15);
      offA[kk][m] = rowA * BK + ((c16 ^ (rowA & 7)) << 3);
      int rowB = wc * 64 + m * 16 + (lane & 15);
      offB[kk][m] = rowB * BK + ((c16 ^ (rowB & 7)) << 3);
    }
  }

  f32x4 acc[4][4] = {};

  const unsigned short* Abase = A + (size_t)rowBase * IN_DIM;
  const unsigned short* Bbase = B + (size_t)colBase * IN_DIM;

  for (int k0 = 0; k0 < IN_DIM; k0 += BK) {
#pragma unroll
    for (int it = 0; it < 4; ++it) {
      int ch = it * 256 + tid;
      gload_lds16(Abase + (size_t)sRow[it] * IN_DIM + k0 + sCol[it], &ldsA[ch * 8]);
      gload_lds16(Bbase + (size_t)sRow[it] * IN_DIM + k0 + sCol[it], &ldsB[ch * 8]);
    }
    __syncthreads();  // compiler emits s_waitcnt vmcnt(0) before s_barrier

#pragma unroll
    for (int kk = 0; kk < 2; ++kk) {
      s16x8 a[4], b[4];
#pragma unroll
      for (int m = 0; m < 4; ++m) a[m] = *reinterpret_cast<const s16x8*>(&ldsA[offA[kk][m]]);
#pragma unroll
      for (int n = 0; n < 4; ++n) b[n] = *reinterpret_cast<const s16x8*>(&ldsB[offB[kk][n]]);
#pragma unroll
      for (int m = 0; m < 4; ++m)
#pragma unroll
        for (int n = 0; n < 4; ++n)
          acc[m][n] = __builtin_amdgcn_mfma_f32_16x16x32_bf16(a[m], b[n], acc[m][n], 0, 0, 0);
    }
    __syncthreads();
  }

  // Epilogue: C/D layout (m89-verified): col = lane&15, row = (lane>>4)*4 + j
#pragma unroll
  for (int m = 0; m < 4; ++m) {
    int row0 = rowBase + wr * 64 + m * 16 + ((lane >> 4) << 2);
#pragma unroll
    for (int n = 0; n < 4; ++n) {
      int col = colBase + wc * 64 + n * 16 + (lane & 15);
#pragma unroll
      for (int j = 0; j < 4; ++j) {
        C[(size_t)(row0 + j) * VOCAB + col] = acc[m][n][j];
      }
    }
  }
}

// ---------- fused per-row softmax (in place over logits) ----------
__global__ __launch_bounds__(256) void row_softmax(float* __restrict__ C) {
  const int row = blockIdx.x;
  float* p = C + (size_t)row * VOCAB;
  const int tid = threadIdx.x;
  const int NQ = VOCAB / 4;  // 8000 float4

  float m = -3.4e38f, s = 0.f;
  for (int i = tid; i < NQ; i += 256) {
    float4 v = reinterpret_cast<const float4*>(p)[i];
    float mv = fmaxf(fmaxf(v.x, v.y), fmaxf(v.z, v.w));
    if (mv > m) {
      s *= __expf(m - mv);
      m = mv;
    }
    s += __expf(v.x - m) + __expf(v.y - m) + __expf(v.z - m) + __expf(v.w - m);
  }
  // wave reduce (64 lanes)
#pragma unroll
  for (int off = 32; off > 0; off >>= 1) {
    float m2 = __shfl_down(m, off);
    float s2 = __shfl_down(s, off);
    float M = fmaxf(m, m2);
    s = s * __expf(m - M) + s2 * __expf(m2 - M);
    m = M;
  }
  __shared__ float redM[4], redS[4];
  if ((tid & 63) == 0) {
    redM[tid >> 6] = m;
    redS[tid >> 6] = s;
  }
  __syncthreads();
  if (tid == 0) {
    float M = redM[0], S = redS[0];
#pragma unroll
    for (int w = 1; w < 4; ++w) {
      float M2 = fmaxf(M, redM[w]);
      S = S * __expf(M - M2) + redS[w] * __expf(redM[w] - M2);
      M = M2;
    }
    redM[0] = M;
    redS[0] = 1.f / S;
  }
  __syncthreads();
  const float M = redM[0], invS = redS[0];
  for (int i = tid; i < NQ; i += 256) {
    float4 v = reinterpret_cast<const float4*>(p)[i];
    v.x = __expf(v.x - M) * invS;
    v.y = __expf(v.y - M) * invS;
    v.z = __expf(v.z - M) * invS;
    v.w = __expf(v.w - M) * invS;
    reinterpret_cast<float4*>(p)[i] = v;
  }
}

extern "C" void kernel_launch(void* const* d_in, const int* in_sizes, int n_in,
                              void* d_out, int out_size, void* d_ws, size_t ws_size,
                              hipStream_t stream) {
  const float* x = (const float*)d_in[0];
  // d_in[1] = target (int64), unused by the reference forward
  const float* w = (const float*)d_in[2];
  float* out = (float*)d_out;

  // workspace layout: X_bf16 [2048*2048] then W_bf16 [32000*2048]
  // (requires ws_size >= 139,460,608 bytes)
  unsigned short* xbf = (unsigned short*)d_ws;
  unsigned short* wbf = xbf + (size_t)TOKENS * IN_DIM;

  convert_f32_to_bf16<<<512, 256, 0, stream>>>(x, xbf, TOKENS * IN_DIM / 4);
  convert_f32_to_bf16<<<2048, 256, 0, stream>>>(w, wbf, VOCAB * IN_DIM / 4);
  gemm_bt<<<GEMM_GRID, 256, 0, stream>>>(xbf, wbf, out);
  row_softmax<<<TOKENS, 256, 0, stream>>>(out);
}

// Round 2
// 526.398 us; speedup vs baseline: 1.2174x; 1.2174x over previous
//
#include <hip/hip_runtime.h>
#include <hip/hip_bf16.h>
#include <math.h>

#define TOKENS 2048
#define IN_DIM 2048
#define VOCAB  32000

#define BM 256
#define BN 256
#define BK 64
#define NKSTEP (IN_DIM / BK)                    // 32
#define GEMM_GRID ((TOKENS / BM) * (VOCAB / BN)) // 8 * 125 = 1000

typedef short s16x8 __attribute__((ext_vector_type(8)));
typedef float f32x4 __attribute__((ext_vector_type(4)));

// ---------- fp32 -> bf16 (round-to-nearest-even) ----------
__device__ __forceinline__ unsigned short f2bf_rne(float f) {
  unsigned int u = __float_as_uint(f);
  u += 0x7fffu + ((u >> 16) & 1u);
  return (unsigned short)(u >> 16);
}

__global__ __launch_bounds__(256) void convert_f32_to_bf16(
    const float* __restrict__ in, unsigned short* __restrict__ out, int n4) {
  int idx = blockIdx.x * blockDim.x + threadIdx.x;
  int stride = gridDim.x * blockDim.x;
  for (int i = idx; i < n4; i += stride) {
    float4 v = reinterpret_cast<const float4*>(in)[i];
    ushort4 o;
    o.x = f2bf_rne(v.x);
    o.y = f2bf_rne(v.y);
    o.z = f2bf_rne(v.z);
    o.w = f2bf_rne(v.w);
    reinterpret_cast<ushort4*>(out)[i] = o;
  }
}

// ---------- async global -> LDS, 16B per lane ----------
__device__ __forceinline__ void gload_lds16(const unsigned short* g, unsigned short* l) {
  __builtin_amdgcn_global_load_lds(
      (const __attribute__((address_space(1))) unsigned int*)g,
      (__attribute__((address_space(3))) unsigned int*)l, 16, 0, 0);
}

// ---------- 256x256 8-phase GEMM: C[t][v] = sum_k Xbf[t][k] * Wbf[v][k] ----------
// 8 waves (2Mx4N), per-wave 128x64 out. LDS: 2 buffers x (A[256][64]+B[256][64]) bf16
// = 128 KiB. Chunk-XOR swizzle (c16 ^= row&7), applied on source+read, linear dest.
// Per K-step: 4 phases {12,8,4,0} ds_reads + 1 half-tile stage each + 16 MFMA each;
// one counted vmcnt(2) per K-step (phase 3), raw s_barrier (no vmcnt(0) drain).
__global__ __launch_bounds__(512, 2) void gemm_bt(
    const unsigned short* __restrict__ A,   // [TOKENS][IN_DIM] bf16
    const unsigned short* __restrict__ B,   // [VOCAB][IN_DIM] bf16
    float* __restrict__ C) {                // [TOKENS][VOCAB] logits
  __shared__ __align__(16) unsigned short lds[65536];  // 128 KiB

  const int tid = threadIdx.x;   // 0..511
  const int lane = tid & 63;
  const int wave = tid >> 6;     // 0..7
  const int wr = wave >> 2;      // 0..1  (M)
  const int wc = wave & 3;       // 0..3  (N)

  // XCD swizzle (1000 % 8 == 0), then rowTile-major within XCD (8 blocks share a W panel)
  const int bid = blockIdx.x;
  const int lid = (bid & 7) * (GEMM_GRID / 8) + (bid >> 3);
  const int rowTile = lid & 7;
  const int colTile = lid >> 3;
  const int rowBase = rowTile * BM;
  const int colBase = colTile * BN;

  // ---- staging geometry: half-tile = 128 rows x 64 cols = 1024 chunks of 16B;
  // thread stages chunks {tid, 512+tid}. Source col pre-inverse-swizzled.
  const int r0 = tid >> 3;                       // 0..63
  const int r1 = 64 + r0;                        // 64..127 (r1&7 == r0&7)
  const int c8 = (((tid & 7) ^ (r0 & 7)) << 3);  // ushort offset in row
  const unsigned short* srcA0 = A + (size_t)(rowBase + r0) * IN_DIM + c8;
  const unsigned short* srcA1 = A + (size_t)(rowBase + r1) * IN_DIM + c8;
  const unsigned short* srcB0 = B + (size_t)(colBase + r0) * IN_DIM + c8;
  const unsigned short* srcB1 = B + (size_t)(colBase + r1) * IN_DIM + c8;
  const int ldsD0 = tid * 8;          // ushort dst offset within area
  const int ldsD1 = (512 + tid) * 8;

  auto stageA = [&](int buf, int h, int k) {
    size_t off = (size_t)h * (128 * IN_DIM) + k;
    int dst = buf * 32768 + h * 8192;
    gload_lds16(srcA0 + off, &lds[dst + ldsD0]);
    gload_lds16(srcA1 + off, &lds[dst + ldsD1]);
  };
  auto stageB = [&](int buf, int h, int k) {
    size_t off = (size_t)h * (128 * IN_DIM) + k;
    int dst = 16384 + buf * 32768 + h * 8192;
    gload_lds16(srcB0 + off, &lds[dst + ldsD0]);
    gload_lds16(srcB1 + off, &lds[dst + ldsD1]);
  };

  // ---- ds_read geometry (swizzle on read); row&7 == lane&7 for all fragments
  const int sc0 = (((lane >> 4) ^ (lane & 7)) << 3);        // kk=0 chunk
  const int sc1 = (((4 + (lane >> 4)) ^ (lane & 7)) << 3);  // kk=1 chunk
  const int aRow = (wr * 128 + (lane & 15)) * 64;
  const int bRow = 16384 + (wc * 64 + (lane & 15)) * 64;

#define LDA(buf, m, kk) (*(const s16x8*)&lds[(buf) * 32768 + aRow + (m) * 1024 + ((kk) ? sc1 : sc0)])
#define LDB(buf, n, kk) (*(const s16x8*)&lds[(buf) * 32768 + bRow + (n) * 1024 + ((kk) ? sc1 : sc0)])

  f32x4 acc[8][4] = {};

  // ---- prologue: step0 fully + (A,h0) of step1; counted drain
  stageA(0, 0, 0);
  stageA(0, 1, 0);
  stageB(0, 0, 0);
  stageB(0, 1, 0);
  stageA(1, 0, 64);
  asm volatile("s_waitcnt vmcnt(2)" ::: "memory");
  __builtin_amdgcn_s_barrier();

#define KSTEP(bufc, kc, kn1, kn2)                                                   \
  {                                                                                 \
    s16x8 aL[4][2], aH[4][2], bL[2][2], bH[2][2];                                   \
    /* P0: read A m0-3 + B n0-1 (12 reads); stage (A,h1) of step+1 */               \
    _Pragma("unroll") for (int m = 0; m < 4; ++m) {                                 \
      aL[m][0] = LDA(bufc, m, 0);                                                   \
      aL[m][1] = LDA(bufc, m, 1);                                                   \
    }                                                                               \
    _Pragma("unroll") for (int n = 0; n < 2; ++n) {                                 \
      bL[n][0] = LDB(bufc, n, 0);                                                   \
      bL[n][1] = LDB(bufc, n, 1);                                                   \
    }                                                                               \
    stageA((bufc) ^ 1, 1, kn1);                                                     \
    asm volatile("s_waitcnt lgkmcnt(8)" ::: "memory");                              \
    __builtin_amdgcn_s_barrier();                                                   \
    asm volatile("s_waitcnt lgkmcnt(0)" ::: "memory");                              \
    __builtin_amdgcn_s_setprio(1);                                                  \
    _Pragma("unroll") for (int m = 0; m < 4; ++m)                                   \
        _Pragma("unroll") for (int n = 0; n < 2; ++n) {                             \
      acc[m][n] = __builtin_amdgcn_mfma_f32_16x16x32_bf16(aL[m][0], bL[n][0], acc[m][n], 0, 0, 0); \
      acc[m][n] = __builtin_amdgcn_mfma_f32_16x16x32_bf16(aL[m][1], bL[n][1], acc[m][n], 0, 0, 0); \
    }                                                                               \
    __builtin_amdgcn_s_setprio(0);                                                  \
    __builtin_amdgcn_s_barrier();                                                   \
    /* P1: read A m4-7 (8); stage (B,h0) of step+1 */                               \
    _Pragma("unroll") for (int m = 0; m < 4; ++m) {                                 \
      aH[m][0] = LDA(bufc, 4 + m, 0);                                               \
      aH[m][1] = LDA(bufc, 4 + m, 1);                                               \
    }                                                                               \
    stageB((bufc) ^ 1, 0, kn1);                                                     \
    __builtin_amdgcn_s_barrier();                                                   \
    asm volatile("s_waitcnt lgkmcnt(0)" ::: "memory");                              \
    __builtin_amdgcn_s_setprio(1);                                                  \
    _Pragma("unroll") for (int m = 0; m < 4; ++m)                                   \
        _Pragma("unroll") for (int n = 0; n < 2; ++n) {                             \
      acc[4 + m][n] = __builtin_amdgcn_mfma_f32_16x16x32_bf16(aH[m][0], bL[n][0], acc[4 + m][n], 0, 0, 0); \
      acc[4 + m][n] = __builtin_amdgcn_mfma_f32_16x16x32_bf16(aH[m][1], bL[n][1], acc[4 + m][n], 0, 0, 0); \
    }                                                                               \
    __builtin_amdgcn_s_setprio(0);                                                  \
    __builtin_amdgcn_s_barrier();                                                   \
    /* P2: read B n2-3 (4); stage (B,h1) of step+1 */                               \
    _Pragma("unroll") for (int n = 0; n < 2; ++n) {                                 \
      bH[n][0] = LDB(bufc, 2 + n, 0);                                               \
      bH[n][1] = LDB(bufc, 2 + n, 1);                                               \
    }                                                                               \
    stageB((bufc) ^ 1, 1, kn1);                                                     \
    __builtin_amdgcn_s_barrier();                                                   \
    asm volatile("s_waitcnt lgkmcnt(0)" ::: "memory");                              \
    __builtin_amdgcn_s_setprio(1);                                                  \
    _Pragma("unroll") for (int m = 0; m < 4; ++m)                                   \
        _Pragma("unroll") for (int n = 0; n < 2; ++n) {                             \
      acc[4 + m][2 + n] = __builtin_amdgcn_mfma_f32_16x16x32_bf16(aH[m][0], bH[n][0], acc[4 + m][2 + n], 0, 0, 0); \
      acc[4 + m][2 + n] = __builtin_amdgcn_mfma_f32_16x16x32_bf16(aH[m][1], bH[n][1], acc[4 + m][2 + n], 0, 0, 0); \
    }                                                                               \
    __builtin_amdgcn_s_setprio(0);                                                  \
    __builtin_amdgcn_s_barrier();                                                   \
    /* P3: no reads; stage (A,h0) of step+2 into SAME buf (dead after P2 barrier); */ \
    /* counted vmcnt: all 4 half-tiles of step+1 landed, only this pair in flight */ \
    stageA((bufc), 0, kn2);                                                         \
    asm volatile("s_waitcnt vmcnt(2)" ::: "memory");                                \
    __builtin_amdgcn_s_barrier();                                                   \
    __builtin_amdgcn_s_setprio(1);                                                  \
    _Pragma("unroll") for (int m = 0; m < 4; ++m)                                   \
        _Pragma("unroll") for (int n = 0; n < 2; ++n) {                             \
      acc[m][2 + n] = __builtin_amdgcn_mfma_f32_16x16x32_bf16(aL[m][0], bH[n][0], acc[m][2 + n], 0, 0, 0); \
      acc[m][2 + n] = __builtin_amdgcn_mfma_f32_16x16x32_bf16(aL[m][1], bH[n][1], acc[m][2 + n], 0, 0, 0); \
    }                                                                               \
    __builtin_amdgcn_s_setprio(0);                                                  \
    __builtin_amdgcn_s_barrier();                                                   \
  }

  for (int i = 0; i < NKSTEP / 2; ++i) {
    const int k = i * 128;
    KSTEP(0, k, (k + 64) & (IN_DIM - 1), (k + 128) & (IN_DIM - 1));
    KSTEP(1, k + 64, (k + 128) & (IN_DIM - 1), (k + 192) & (IN_DIM - 1));
  }

  asm volatile("s_waitcnt vmcnt(0)" ::: "memory");

  // ---- epilogue: C/D layout col=lane&15, row=(lane>>4)*4+j
#pragma unroll
  for (int m = 0; m < 8; ++m) {
    int row0 = rowBase + wr * 128 + m * 16 + ((lane >> 4) << 2);
#pragma unroll
    for (int n = 0; n < 4; ++n) {
      int col = colBase + wc * 64 + n * 16 + (lane & 15);
#pragma unroll
      for (int j = 0; j < 4; ++j) {
        C[(size_t)(row0 + j) * VOCAB + col] = acc[m][n][j];
      }
    }
  }
#undef LDA
#undef LDB
#undef KSTEP
}

// ---------- fused per-row softmax (in place over logits) ----------
__global__ __launch_bounds__(256) void row_softmax(float* __restrict__ C) {
  const int row = blockIdx.x;
  float* p = C + (size_t)row * VOCAB;
  const int tid = threadIdx.x;
  const int NQ = VOCAB / 4;  // 8000 float4

  float m = -3.4e38f, s = 0.f;
  for (int i = tid; i < NQ; i += 256) {
    float4 v = reinterpret_cast<const float4*>(p)[i];
    float mv = fmaxf(fmaxf(v.x, v.y), fmaxf(v.z, v.w));
    if (mv > m) {
      s *= __expf(m - mv);
      m = mv;
    }
    s += __expf(v.x - m) + __expf(v.y - m) + __expf(v.z - m) + __expf(v.w - m);
  }
#pragma unroll
  for (int off = 32; off > 0; off >>= 1) {
    float m2 = __shfl_down(m, off);
    float s2 = __shfl_down(s, off);
    float M = fmaxf(m, m2);
    s = s * __expf(m - M) + s2 * __expf(m2 - M);
    m = M;
  }
  __shared__ float redM[4], redS[4];
  if ((tid & 63) == 0) {
    redM[tid >> 6] = m;
    redS[tid >> 6] = s;
  }
  __syncthreads();
  if (tid == 0) {
    float M = redM[0], S = redS[0];
#pragma unroll
    for (int w = 1; w < 4; ++w) {
      float M2 = fmaxf(M, redM[w]);
      S = S * __expf(M - M2) + redS[w] * __expf(redM[w] - M2);
      M = M2;
    }
    redM[0] = M;
    redS[0] = 1.f / S;
  }
  __syncthreads();
  const float M = redM[0], invS = redS[0];
  for (int i = tid; i < NQ; i += 256) {
    float4 v = reinterpret_cast<const float4*>(p)[i];
    v.x = __expf(v.x - M) * invS;
    v.y = __expf(v.y - M) * invS;
    v.z = __expf(v.z - M) * invS;
    v.w = __expf(v.w - M) * invS;
    reinterpret_cast<float4*>(p)[i] = v;
  }
}

extern "C" void kernel_launch(void* const* d_in, const int* in_sizes, int n_in,
                              void* d_out, int out_size, void* d_ws, size_t ws_size,
                              hipStream_t stream) {
  const float* x = (const float*)d_in[0];
  // d_in[1] = target (int64), unused by the reference forward
  const float* w = (const float*)d_in[2];
  float* out = (float*)d_out;

  unsigned short* xbf = (unsigned short*)d_ws;
  unsigned short* wbf = xbf + (size_t)TOKENS * IN_DIM;

  convert_f32_to_bf16<<<512, 256, 0, stream>>>(x, xbf, TOKENS * IN_DIM / 4);
  convert_f32_to_bf16<<<2048, 256, 0, stream>>>(w, wbf, VOCAB * IN_DIM / 4);
  gemm_bt<<<GEMM_GRID, 512, 0, stream>>>(xbf, wbf, out);
  row_softmax<<<TOKENS, 256, 0, stream>>>(out);
}

// Round 3
// 485.943 us; speedup vs baseline: 1.3187x; 1.0833x over previous
//
#include <hip/hip_runtime.h>
#include <hip/hip_bf16.h>
#include <math.h>

#define TOKENS 2048
#define IN_DIM 2048
#define VOCAB  32000

#define BM 256
#define BN 256
#define BK 64
#define NKSTEP (IN_DIM / BK)                     // 32
#define GEMM_GRID ((TOKENS / BM) * (VOCAB / BN)) // 8 * 125 = 1000
#define NCT (VOCAB / BN)                         // 125 col tiles

typedef short s16x8 __attribute__((ext_vector_type(8)));
typedef float f32x4 __attribute__((ext_vector_type(4)));

// ---------- fp32 -> bf16 (round-to-nearest-even) ----------
__device__ __forceinline__ unsigned short f2bf_rne(float f) {
  unsigned int u = __float_as_uint(f);
  u += 0x7fffu + ((u >> 16) & 1u);
  return (unsigned short)(u >> 16);
}

__global__ __launch_bounds__(256) void convert_f32_to_bf16(
    const float* __restrict__ in, unsigned short* __restrict__ out, int n4) {
  int idx = blockIdx.x * blockDim.x + threadIdx.x;
  int stride = gridDim.x * blockDim.x;
  for (int i = idx; i < n4; i += stride) {
    float4 v = reinterpret_cast<const float4*>(in)[i];
    ushort4 o;
    o.x = f2bf_rne(v.x);
    o.y = f2bf_rne(v.y);
    o.z = f2bf_rne(v.z);
    o.w = f2bf_rne(v.w);
    reinterpret_cast<ushort4*>(out)[i] = o;
  }
}

// ---------- async global -> LDS, 16B per lane ----------
__device__ __forceinline__ void gload_lds16(const unsigned short* g, unsigned short* l) {
  __builtin_amdgcn_global_load_lds(
      (const __attribute__((address_space(1))) unsigned int*)g,
      (__attribute__((address_space(3))) unsigned int*)l, 16, 0, 0);
}

// ---------- 256x256 8-phase GEMM + fused per-tile softmax partials ----------
// Staging schedule (deep pipeline, 2 LDS buffers, dead-slot reuse):
//   t.P0: stage B h1(t+1)   [slot dead since t-1.P2 barrier]
//   t.P2: stage A h0,h1(t+2)[A slots of bufc dead after t.P1 barrier]
//   t.P3: stage B h0(t+2)   [B h0 of bufc dead after t.P2 barrier]
//   single counted vmcnt(6) at t.P3 AFTER the register-only MFMA:
//   outstanding = Bh1(t+1)2 + A(t+2)4 + Bh0(t+2)2 = 8 -> vmcnt(6) retires Bh1(t+1).
__global__ __launch_bounds__(512, 2) void gemm_bt(
    const unsigned short* __restrict__ A,   // [TOKENS][IN_DIM] bf16
    const unsigned short* __restrict__ B,   // [VOCAB][IN_DIM] bf16
    float* __restrict__ C,                  // [TOKENS][VOCAB] logits
    float2* __restrict__ partials) {        // [TOKENS][NCT] (tile max, tile sumexp)
  __shared__ __align__(16) unsigned short lds[65536];  // 128 KiB

  const int tid = threadIdx.x;   // 0..511
  const int lane = tid & 63;
  const int wave = tid >> 6;     // 0..7
  const int wr = wave >> 2;      // 0..1  (M)
  const int wc = wave & 3;       // 0..3  (N)

  const int bid = blockIdx.x;
  const int lid = (bid & 7) * (GEMM_GRID / 8) + (bid >> 3);
  const int rowTile = lid & 7;
  const int colTile = lid >> 3;
  const int rowBase = rowTile * BM;
  const int colBase = colTile * BN;

  // staging geometry: half-tile = 128 rows x 64 cols = 1024 chunks of 16B
  const int r0 = tid >> 3;
  const int r1 = 64 + r0;
  const int c8 = (((tid & 7) ^ (r0 & 7)) << 3);
  const unsigned short* srcA0 = A + (size_t)(rowBase + r0) * IN_DIM + c8;
  const unsigned short* srcA1 = A + (size_t)(rowBase + r1) * IN_DIM + c8;
  const unsigned short* srcB0 = B + (size_t)(colBase + r0) * IN_DIM + c8;
  const unsigned short* srcB1 = B + (size_t)(colBase + r1) * IN_DIM + c8;
  const int ldsD0 = tid * 8;
  const int ldsD1 = (512 + tid) * 8;

  auto stageA = [&](int buf, int h, int k) {
    size_t off = (size_t)h * (128 * IN_DIM) + k;
    int dst = buf * 32768 + h * 8192;
    gload_lds16(srcA0 + off, &lds[dst + ldsD0]);
    gload_lds16(srcA1 + off, &lds[dst + ldsD1]);
  };
  auto stageB = [&](int buf, int h, int k) {
    size_t off = (size_t)h * (128 * IN_DIM) + k;
    int dst = 16384 + buf * 32768 + h * 8192;
    gload_lds16(srcB0 + off, &lds[dst + ldsD0]);
    gload_lds16(srcB1 + off, &lds[dst + ldsD1]);
  };

  const int sc0 = (((lane >> 4) ^ (lane & 7)) << 3);
  const int sc1 = (((4 + (lane >> 4)) ^ (lane & 7)) << 3);
  const int aRow = (wr * 128 + (lane & 15)) * 64;
  const int bRow = 16384 + (wc * 64 + (lane & 15)) * 64;

#define LDA(buf, m, kk) (*(const s16x8*)&lds[(buf) * 32768 + aRow + (m) * 1024 + ((kk) ? sc1 : sc0)])
#define LDB(buf, n, kk) (*(const s16x8*)&lds[(buf) * 32768 + bRow + (n) * 1024 + ((kk) ? sc1 : sc0)])

  f32x4 acc[8][4] = {};

  // ---- prologue: step0 (8) + A(1) (4) + Bh0(1) (2); vmcnt(6) retires step0
  stageA(0, 0, 0);
  stageA(0, 1, 0);
  stageB(0, 0, 0);
  stageB(0, 1, 0);
  stageA(1, 0, 64);
  stageA(1, 1, 64);
  stageB(1, 0, 64);
  asm volatile("s_waitcnt vmcnt(6)" ::: "memory");
  __builtin_amdgcn_s_barrier();

#define KSTEP(bufc, kn1, kn2)                                                       \
  {                                                                                 \
    s16x8 aL[4][2], aH[4][2], bL[2][2], bH[2][2];                                   \
    /* P0: 12 reads; stage B h1(t+1) -> buf^1 @kn1 */                               \
    _Pragma("unroll") for (int m = 0; m < 4; ++m) {                                 \
      aL[m][0] = LDA(bufc, m, 0);                                                   \
      aL[m][1] = LDA(bufc, m, 1);                                                   \
    }                                                                               \
    _Pragma("unroll") for (int n = 0; n < 2; ++n) {                                 \
      bL[n][0] = LDB(bufc, n, 0);                                                   \
      bL[n][1] = LDB(bufc, n, 1);                                                   \
    }                                                                               \
    stageB((bufc) ^ 1, 1, kn1);                                                     \
    asm volatile("s_waitcnt lgkmcnt(8)" ::: "memory");                              \
    __builtin_amdgcn_s_barrier();                                                   \
    asm volatile("s_waitcnt lgkmcnt(0)" ::: "memory");                              \
    __builtin_amdgcn_s_setprio(1);                                                  \
    _Pragma("unroll") for (int m = 0; m < 4; ++m)                                   \
        _Pragma("unroll") for (int n = 0; n < 2; ++n) {                             \
      acc[m][n] = __builtin_amdgcn_mfma_f32_16x16x32_bf16(aL[m][0], bL[n][0], acc[m][n], 0, 0, 0); \
      acc[m][n] = __builtin_amdgcn_mfma_f32_16x16x32_bf16(aL[m][1], bL[n][1], acc[m][n], 0, 0, 0); \
    }                                                                               \
    __builtin_amdgcn_s_setprio(0);                                                  \
    __builtin_amdgcn_s_barrier();                                                   \
    /* P1: 8 reads aH; no stage */                                                  \
    _Pragma("unroll") for (int m = 0; m < 4; ++m) {                                 \
      aH[m][0] = LDA(bufc, 4 + m, 0);                                               \
      aH[m][1] = LDA(bufc, 4 + m, 1);                                               \
    }                                                                               \
    __builtin_amdgcn_s_barrier();                                                   \
    asm volatile("s_waitcnt lgkmcnt(0)" ::: "memory");                              \
    __builtin_amdgcn_s_setprio(1);                                                  \
    _Pragma("unroll") for (int m = 0; m < 4; ++m)                                   \
        _Pragma("unroll") for (int n = 0; n < 2; ++n) {                             \
      acc[4 + m][n] = __builtin_amdgcn_mfma_f32_16x16x32_bf16(aH[m][0], bL[n][0], acc[4 + m][n], 0, 0, 0); \
      acc[4 + m][n] = __builtin_amdgcn_mfma_f32_16x16x32_bf16(aH[m][1], bL[n][1], acc[4 + m][n], 0, 0, 0); \
    }                                                                               \
    __builtin_amdgcn_s_setprio(0);                                                  \
    __builtin_amdgcn_s_barrier();                                                   \
    /* P2: 4 reads bH; stage A h0,h1(t+2) -> bufc @kn2 (A slots dead since P1 bar) */ \
    _Pragma("unroll") for (int n = 0; n < 2; ++n) {                                 \
      bH[n][0] = LDB(bufc, 2 + n, 0);                                               \
      bH[n][1] = LDB(bufc, 2 + n, 1);                                               \
    }                                                                               \
    stageA((bufc), 0, kn2);                                                         \
    stageA((bufc), 1, kn2);                                                         \
    __builtin_amdgcn_s_barrier();                                                   \
    asm volatile("s_waitcnt lgkmcnt(0)" ::: "memory");                              \
    __builtin_amdgcn_s_setprio(1);                                                  \
    _Pragma("unroll") for (int m = 0; m < 4; ++m)                                   \
        _Pragma("unroll") for (int n = 0; n < 2; ++n) {                             \
      acc[4 + m][2 + n] = __builtin_amdgcn_mfma_f32_16x16x32_bf16(aH[m][0], bH[n][0], acc[4 + m][2 + n], 0, 0, 0); \
      acc[4 + m][2 + n] = __builtin_amdgcn_mfma_f32_16x16x32_bf16(aH[m][1], bH[n][1], acc[4 + m][2 + n], 0, 0, 0); \
    }                                                                               \
    __builtin_amdgcn_s_setprio(0);                                                  \
    __builtin_amdgcn_s_barrier();                                                   \
    /* P3: stage B h0(t+2) -> bufc @kn2 (dead since P2 bar); reg-only MFMA; */      \
    /* counted vmcnt(6) AFTER MFMA retires B h1(t+1) -> buf^1 fully resident */     \
    stageB((bufc), 0, kn2);                                                         \
    __builtin_amdgcn_s_setprio(1);                                                  \
    _Pragma("unroll") for (int m = 0; m < 4; ++m)                                   \
        _Pragma("unroll") for (int n = 0; n < 2; ++n) {                             \
      acc[m][2 + n] = __builtin_amdgcn_mfma_f32_16x16x32_bf16(aL[m][0], bH[n][0], acc[m][2 + n], 0, 0, 0); \
      acc[m][2 + n] = __builtin_amdgcn_mfma_f32_16x16x32_bf16(aL[m][1], bH[n][1], acc[m][2 + n], 0, 0, 0); \
    }                                                                               \
    __builtin_amdgcn_s_setprio(0);                                                  \
    asm volatile("s_waitcnt vmcnt(6)" ::: "memory");                                \
    __builtin_amdgcn_s_barrier();                                                   \
  }

  for (int i = 0; i < NKSTEP / 2; ++i) {
    const int k = i * 128;
    KSTEP(0, (k + 64) & (IN_DIM - 1), (k + 128) & (IN_DIM - 1));
    KSTEP(1, (k + 128) & (IN_DIM - 1), (k + 192) & (IN_DIM - 1));
  }

  // drain wrapped prefetches before LDS reuse
  asm volatile("s_waitcnt vmcnt(0)" ::: "memory");
  __syncthreads();

  // ---- C store: C/D layout col=lane&15, row=(lane>>4)*4+j
#pragma unroll
  for (int m = 0; m < 8; ++m) {
    int row0 = rowBase + wr * 128 + m * 16 + ((lane >> 4) << 2);
#pragma unroll
    for (int n = 0; n < 4; ++n) {
      int col = colBase + wc * 64 + n * 16 + (lane & 15);
#pragma unroll
      for (int j = 0; j < 4; ++j) {
        C[(size_t)(row0 + j) * VOCAB + col] = acc[m][n][j];
      }
    }
  }

  // ---- fused softmax partials over this tile's 256 cols, per row
  // lane-group (same lane>>4) covers one row per (m,jj) across lane&15 x n.
  float* lmax = reinterpret_cast<float*>(lds);   // [256][4]
  float* lsum = lmax + 1024;                     // [256][4]
#pragma unroll
  for (int m = 0; m < 8; ++m) {
#pragma unroll
    for (int jj = 0; jj < 4; ++jj) {
      float v0 = acc[m][0][jj], v1 = acc[m][1][jj], v2 = acc[m][2][jj], v3 = acc[m][3][jj];
      float mx = fmaxf(fmaxf(v0, v1), fmaxf(v2, v3));
#pragma unroll
      for (int off = 1; off < 16; off <<= 1) mx = fmaxf(mx, __shfl_xor(mx, off));
      float s = __expf(v0 - mx) + __expf(v1 - mx) + __expf(v2 - mx) + __expf(v3 - mx);
#pragma unroll
      for (int off = 1; off < 16; off <<= 1) s += __shfl_xor(s, off);
      if ((lane & 15) == 0) {
        int r = wr * 128 + m * 16 + ((lane >> 4) << 2) + jj;
        lmax[r * 4 + wc] = mx;
        lsum[r * 4 + wc] = s;
      }
    }
  }
  __syncthreads();
  if (tid < 256) {
    float m0 = lmax[tid * 4 + 0], m1 = lmax[tid * 4 + 1];
    float m2 = lmax[tid * 4 + 2], m3 = lmax[tid * 4 + 3];
    float M = fmaxf(fmaxf(m0, m1), fmaxf(m2, m3));
    float S = lsum[tid * 4 + 0] * __expf(m0 - M) + lsum[tid * 4 + 1] * __expf(m1 - M) +
              lsum[tid * 4 + 2] * __expf(m2 - M) + lsum[tid * 4 + 3] * __expf(m3 - M);
    partials[(size_t)(rowBase + tid) * NCT + colTile] = make_float2(M, S);
  }
#undef LDA
#undef LDB
#undef KSTEP
}

// ---------- combine per-tile partials -> per-row (max, 1/sum) ----------
__global__ __launch_bounds__(256) void reduce_stats(
    const float2* __restrict__ partials, float2* __restrict__ stats) {
  int row = blockIdx.x * blockDim.x + threadIdx.x;
  if (row >= TOKENS) return;
  const float2* p = partials + (size_t)row * NCT;
  float M = -3.4e38f, S = 0.f;
  for (int i = 0; i < NCT; ++i) {
    float2 v = p[i];
    if (v.x > M) {
      S *= __expf(M - v.x);
      M = v.x;
    }
    S += v.y * __expf(v.x - M);
  }
  stats[row] = make_float2(M, 1.f / S);
}

// ---------- apply: single read+write pass over logits ----------
__global__ __launch_bounds__(256) void apply_softmax(
    float* __restrict__ C, const float2* __restrict__ stats) {
  const int row = blockIdx.x;
  float* p = C + (size_t)row * VOCAB;
  const float2 st = stats[row];
  const float M = st.x, invS = st.y;
  const int NQ = VOCAB / 4;  // 8000
  for (int i = threadIdx.x; i < NQ; i += 256) {
    float4 v = reinterpret_cast<const float4*>(p)[i];
    v.x = __expf(v.x - M) * invS;
    v.y = __expf(v.y - M) * invS;
    v.z = __expf(v.z - M) * invS;
    v.w = __expf(v.w - M) * invS;
    reinterpret_cast<float4*>(p)[i] = v;
  }
}

extern "C" void kernel_launch(void* const* d_in, const int* in_sizes, int n_in,
                              void* d_out, int out_size, void* d_ws, size_t ws_size,
                              hipStream_t stream) {
  const float* x = (const float*)d_in[0];
  // d_in[1] = target (int64), unused by the reference forward
  const float* w = (const float*)d_in[2];
  float* out = (float*)d_out;

  // ws layout: xbf 8MB | wbf 131MB | partials 2.05MB | stats 16KB  (~141.6MB)
  unsigned short* xbf = (unsigned short*)d_ws;
  unsigned short* wbf = xbf + (size_t)TOKENS * IN_DIM;
  float2* partials = (float2*)(wbf + (size_t)VOCAB * IN_DIM);
  float2* stats = partials + (size_t)TOKENS * NCT;

  convert_f32_to_bf16<<<512, 256, 0, stream>>>(x, xbf, TOKENS * IN_DIM / 4);
  convert_f32_to_bf16<<<2048, 256, 0, stream>>>(w, wbf, VOCAB * IN_DIM / 4);
  gemm_bt<<<GEMM_GRID, 512, 0, stream>>>(xbf, wbf, out, partials);
  reduce_stats<<<TOKENS / 256, 256, 0, stream>>>(partials, stats);
  apply_softmax<<<TOKENS, 256, 0, stream>>>(out, stats);
}